// Round 2
// 837.113 us; speedup vs baseline: 1.5435x; 1.5435x over previous
//
#include <hip/hip_runtime.h>

#define DIM  256
#define NH   4
#define HC   64
#define NTOK 49

typedef short bf16x8 __attribute__((ext_vector_type(8)));
typedef short bf16x4 __attribute__((ext_vector_type(4)));
typedef float f32x4  __attribute__((ext_vector_type(4)));

#define MFMA(a, b, c) __builtin_amdgcn_mfma_f32_16x16x32_bf16((a), (b), (c), 0, 0, 0)
#define LGKM0() asm volatile("s_waitcnt lgkmcnt(0)" ::: "memory")
#define BAR()   __builtin_amdgcn_s_barrier()

template<int N> __device__ __forceinline__ void vmwait() {
    asm volatile("s_waitcnt vmcnt(%0)" :: "n"(N) : "memory");
}

// async global->LDS, 16B per lane; LDS dest is wave-uniform base + lane*16
__device__ __forceinline__ void gload16(const void* g, void* l) {
    __builtin_amdgcn_global_load_lds(
        (const __attribute__((address_space(1))) unsigned int*)g,
        (__attribute__((address_space(3))) unsigned int*)l, 16, 0, 0);
}

__device__ __forceinline__ short f2bf(float f) {
    union { float f; unsigned u; } v; v.f = f;
    unsigned r = v.u + 0x7fffu + ((v.u >> 16) & 1u);   // RNE
    return (short)(r >> 16);
}
__device__ __forceinline__ float bf2f(unsigned lo16) {
    union { unsigned u; float f; } v; v.u = lo16 << 16; return v.f;
}
__device__ __forceinline__ unsigned pack2(float a, float b) {
    return (unsigned)(unsigned short)f2bf(a) | ((unsigned)(unsigned short)f2bf(b) << 16);
}
__device__ __forceinline__ float wred_sum16(float v) {
    v += __shfl_xor(v, 1); v += __shfl_xor(v, 2);
    v += __shfl_xor(v, 4); v += __shfl_xor(v, 8);
    return v;
}
__device__ __forceinline__ float wred_max16(float v) {
    v = fmaxf(v, __shfl_xor(v, 1)); v = fmaxf(v, __shfl_xor(v, 2));
    v = fmaxf(v, __shfl_xor(v, 4)); v = fmaxf(v, __shfl_xor(v, 8));
    return v;
}

// ---- chunk issue helpers -------------------------------------------------
// QKV chunk qc in [0,32): (h,H,c) = (qc>>3, (qc>>2)&1, qc&3). 12 tiles of 1KB:
// tile j = (kkl*2+t)*3 + mat, covering kk in {2c, 2c+1}, nt in {2H, 2H+1},
// mats q/k/v. Wave w copies tiles j = i*4+w (3 insts -> vmcnt +=3 per wave).
__device__ __forceinline__ void issue_qkv(const short* __restrict__ Wf, char* qst,
                                          int qc, int w, int lane) {
    const int h = qc >> 3, H = (qc >> 2) & 1, c = qc & 3;
    char* slot = qst + (qc & 1) * 12288;
    #pragma unroll
    for (int i = 0; i < 3; ++i) {
        const int j = i * 4 + w;
        const int mat = j % 3, rem = j / 3;
        const int t = rem & 1, kkl = rem >> 1;
        const int tile = (mat * 16 + h * 4 + 2 * H + t) * 8 + (2 * c + kkl);
        gload16(Wf + tile * 512 + lane * 8, slot + j * 1024);
    }
}

// FFN chunk fc in [0,32): (g,half,kk) = (fc>>4, (fc>>3)&1, fc&7). 8 tiles:
// cidx 0..7 (output col-groups). Wave w copies cidx = i*4+w (2 insts/wave).
__device__ __forceinline__ void issue_ffn(const short* __restrict__ Wf, char* fst,
                                          int fc, int w, int lane) {
    const int g = fc >> 4, half = (fc >> 3) & 1, kk = fc & 7;
    char* slot = fst + (fc & 1) * 8192;
    #pragma unroll
    for (int i = 0; i < 2; ++i) {
        const int cidx = i * 4 + w;
        const int tile = (48 + g * 16 + half * 8 + cidx) * 8 + kk;
        gload16(Wf + tile * 512 + lane * 8, slot + cidx * 1024);
    }
}

// Weight standardization + scatter into MFMA-fragment-major layout (unchanged).
__global__ void prep_w(const float* w0, const float* w1, const float* w2,
                       const float* w3, const float* w4, short* __restrict__ Wf) {
    const float* Ws[5] = {w0, w1, w2, w3, w4};
    const int mat  = blockIdx.y;
    const int k    = blockIdx.x;
    const int lane = threadIdx.x;
    const float* W = Ws[mat];
    #pragma unroll
    for (int h = 0; h < NH; ++h) {
        float w = W[k * DIM + h * HC + lane];
        float s1 = w, s2 = w * w;
        #pragma unroll
        for (int off = 1; off < 64; off <<= 1) {
            s1 += __shfl_xor(s1, off);
            s2 += __shfl_xor(s2, off);
        }
        float m   = s1 * 0.015625f;
        float var = s2 * 0.015625f - m * m;
        float inv = rsqrtf(fmaxf(var, 1e-30f)) * 0.0625f;
        float val = (w - m) * inv;
        int n  = h * HC + lane;
        int nt = n >> 4, nl = n & 15;
        int kk = k >> 5, kl = k & 31;
        Wf[((mat * 16 + nt) * 8 + kk) * 512 + (nl + 16 * (kl >> 3)) * 8 + (kl & 7)] = f2bf(val);
    }
}

__global__ void prep_b(const float* b0, const float* b1, const float* b2,
                       const float* b3, const float* b4, float* __restrict__ Bias) {
    const float* Bs[5] = {b0, b1, b2, b3, b4};
    const int mat = blockIdx.y, h = blockIdx.x, lane = threadIdx.x;
    float w = Bs[mat][h * HC + lane];
    float s1 = w, s2 = w * w;
    #pragma unroll
    for (int off = 1; off < 64; off <<= 1) {
        s1 += __shfl_xor(s1, off);
        s2 += __shfl_xor(s2, off);
    }
    float m   = s1 * 0.015625f;
    float var = s2 * 0.015625f - m * m;
    float inv = rsqrtf(fmaxf(var, 1e-30f)) * 0.0625f;
    Bias[mat * DIM + h * HC + lane] = (w - m) * inv;
}

// One block = one batch item; 4 waves, wave w owns token rows [16w,16w+16).
// LDS map:  [0,27648)      qP/kb/vt (attn)  |  [0,33792) xb / stg (FFN phases)
//           [27648,52224)  QKV stage 2x12KB |  [33792,50176) FFN stage 2x8KB
// All Wf B-tiles stream through LDS via global_load_lds; counted vmcnt keeps
// 2 chunks in flight; raw s_barrier (+lgkmcnt only) so the queue never drains.
__global__ __launch_bounds__(256, 3) void irmb_main(
    const float* __restrict__ x, const short* __restrict__ Wf,
    const float* __restrict__ Bias, float* __restrict__ out)
{
    __shared__ __align__(16) char smem[52224];
    short (*qP)[72]  = (short (*)[72])smem;            //  9216 B, wave-row-private
    short (*kb)[72]  = (short (*)[72])(smem +  9216);  //  9216 B, shared
    short (*vt)[72]  = (short (*)[72])(smem + 18432);  //  9216 B, shared
    short (*xb)[264] = (short (*)[264])smem;           // 33792 B, wave-row-private
    float (*stg)[132] = (float (*)[132])smem;          // 33792 B, wave-row-private
    char* qst = smem + 27648;                          // QKV stage, 2 x 12288
    char* fst = smem + 33792;                          // FFN stage, 2 x 8192

    const int tid = threadIdx.x;
    const int w = tid >> 6, lane = tid & 63;
    const int l15 = lane & 15, qd = lane >> 4;
    const int arow = 16 * w + l15;

    const float* xblk = x + (size_t)blockIdx.x * (NTOK * DIM);
    float* oblk = out + (size_t)blockIdx.x * (NTOK * DIM);

    // ---- x A-fragments straight from global into registers ----
    bf16x8 ax[8];
    {
        const float* xr = xblk + arow * DIM;
        #pragma unroll
        for (int kk = 0; kk < 8; ++kk) {
            f32x4 u = {0.f,0.f,0.f,0.f}, v2 = {0.f,0.f,0.f,0.f};
            if (arow < NTOK) {
                u  = *(const f32x4*)(xr + 32 * kk + 8 * qd);
                v2 = *(const f32x4*)(xr + 32 * kk + 8 * qd + 4);
            }
            bf16x8 a;
            a[0]=f2bf(u[0]);  a[1]=f2bf(u[1]);  a[2]=f2bf(u[2]);  a[3]=f2bf(u[3]);
            a[4]=f2bf(v2[0]); a[5]=f2bf(v2[1]); a[6]=f2bf(v2[2]); a[7]=f2bf(v2[3]);
            ax[kk] = a;
        }
    }

    // prologue: first two QKV chunks in flight
    issue_qkv(Wf, qst, 0, w, lane);
    issue_qkv(Wf, qst, 1, w, lane);

    unsigned x1p[16][2];   // packed bf16 x1 (later x3), C-layout row pairs

    #pragma unroll
    for (int h = 0; h < NH; ++h) {
        float vf[4][4];
        unsigned kp[4][2];

        #pragma unroll
        for (int H = 0; H < 2; ++H) {
            // epilogue operands prefetched BEFORE deeper chunk issues so the
            // compiler's vmcnt waits for them never drain the async queue.
            float xh[2][4], bq_[2], bk_[2], bv_[2];
            #pragma unroll
            for (int t = 0; t < 2; ++t) {
                const int col = h * HC + 16 * (2 * H + t) + l15;
                bq_[t] = Bias[col]; bk_[t] = Bias[DIM + col]; bv_[t] = Bias[2 * DIM + col];
                #pragma unroll
                for (int r = 0; r < 4; ++r) {
                    const int row = 16 * w + 4 * qd + r;
                    xh[t][r] = (row < NTOK) ? xblk[row * DIM + col] : 0.f;
                }
            }

            f32x4 qa[2], ka[2], va[2];
            #pragma unroll
            for (int t = 0; t < 2; ++t) {
                qa[t] = (f32x4){0.f,0.f,0.f,0.f};
                ka[t] = (f32x4){0.f,0.f,0.f,0.f};
                va[t] = (f32x4){0.f,0.f,0.f,0.f};
            }

            #pragma unroll
            for (int c = 0; c < 4; ++c) {
                const int qc = h * 8 + H * 4 + c;
                if (qc == 31) vmwait<0>(); else vmwait<3>();   // chunk qc arrived
                BAR();                                          // ...for every wave
                const short* slot = (const short*)(qst + (qc & 1) * 12288);
                #pragma unroll
                for (int kkl = 0; kkl < 2; ++kkl) {
                    bf16x8 a = ax[2 * c + kkl];
                    #pragma unroll
                    for (int t = 0; t < 2; ++t) {
                        const short* bp = slot + (kkl * 2 + t) * 3 * 512 + lane * 8;
                        bf16x8 bq = *(const bf16x8*)(bp);
                        bf16x8 bk = *(const bf16x8*)(bp + 512);
                        bf16x8 bv = *(const bf16x8*)(bp + 1024);
                        qa[t] = MFMA(a, bq, qa[t]);
                        ka[t] = MFMA(a, bk, ka[t]);
                        va[t] = MFMA(a, bv, va[t]);
                    }
                }
                LGKM0();     // slot reads retired before anyone overwrites it
                BAR();
                if (qc < 30) {
                    issue_qkv(Wf, qst, qc + 2, w, lane);
                } else if (qc == 31) {
                    issue_ffn(Wf, fst, 0, w, lane);   // FFN pipeline starts here,
                    issue_ffn(Wf, fst, 1, w, lane);   // flies across h=3 attention
                }
            }

            #pragma unroll
            for (int t = 0; t < 2; ++t) {
                const int nt = 2 * H + t;
                #pragma unroll
                for (int r = 0; r < 4; ++r) {
                    const int row = 16 * w + 4 * qd + r;
                    qP[row][16 * nt + l15] = f2bf(qa[t][r] + bq_[t]);   // row-private
                    vf[nt][r] = 0.1f * (va[t][r] + bv_[t]) + 0.95f * xh[t][r];
                }
                kp[nt][0] = pack2(ka[t][0] + bk_[t], ka[t][1] + bk_[t]);
                kp[nt][1] = pack2(ka[t][2] + bk_[t], ka[t][3] + bk_[t]);
            }
        }

        if (h) { LGKM0(); BAR(); }       // prior head's kb/vt reads complete
        #pragma unroll
        for (int nt = 0; nt < 4; ++nt) {
            #pragma unroll
            for (int rp = 0; rp < 2; ++rp) {
                kb[16 * w + 4 * qd + 2 * rp    ][16 * nt + l15] = (short)(kp[nt][rp] & 0xffff);
                kb[16 * w + 4 * qd + 2 * rp + 1][16 * nt + l15] = (short)(kp[nt][rp] >> 16);
            }
            bf16x4 vp;
            vp[0] = f2bf(vf[nt][0]); vp[1] = f2bf(vf[nt][1]);
            vp[2] = f2bf(vf[nt][2]); vp[3] = f2bf(vf[nt][3]);
            *(bf16x4*)&vt[16 * nt + l15][16 * w + 4 * qd] = vp;   // [channel][token]
        }
        LGKM0(); BAR();                  // kb/vt ready (lgkm only: no vmcnt drain)

        // ---- S = 0.125 * q @ k^T ----
        f32x4 sa[4];
        #pragma unroll
        for (int nt = 0; nt < 4; ++nt) sa[nt] = (f32x4){0.f,0.f,0.f,0.f};
        #pragma unroll
        for (int kk = 0; kk < 2; ++kk) {
            bf16x8 a = *(const bf16x8*)&qP[arow][32 * kk + 8 * qd];
            #pragma unroll
            for (int nt = 0; nt < 4; ++nt) {
                bf16x8 bb = *(const bf16x8*)&kb[16 * nt + l15][32 * kk + 8 * qd];
                sa[nt] = MFMA(a, bb, sa[nt]);
            }
        }

        // ---- softmax over keys (mask cols >= 49) ----
        float pmat[4][4];
        #pragma unroll
        for (int r = 0; r < 4; ++r) {
            float vals[4];
            #pragma unroll
            for (int nt = 0; nt < 4; ++nt) {
                const int ck = 16 * nt + l15;
                vals[nt] = (ck < NTOK) ? sa[nt][r] * 0.125f : -3.0e38f;
            }
            float mx = fmaxf(fmaxf(vals[0], vals[1]), fmaxf(vals[2], vals[3]));
            mx = wred_max16(mx);
            float sum = 0.f;
            #pragma unroll
            for (int nt = 0; nt < 4; ++nt) {
                const int ck = 16 * nt + l15;
                const float p = (ck < NTOK) ? __expf(vals[nt] - mx) : 0.f;
                pmat[nt][r] = p;
                sum += p;
            }
            sum = wred_sum16(sum);
            const float rs = 1.0f / sum;
            #pragma unroll
            for (int nt = 0; nt < 4; ++nt) pmat[nt][r] *= rs;
        }
        #pragma unroll
        for (int nt = 0; nt < 4; ++nt)
            #pragma unroll
            for (int r = 0; r < 4; ++r)
                qP[16 * w + 4 * qd + r][16 * nt + l15] = f2bf(pmat[nt][r]);
        LGKM0();   // same-wave cross-lane: P writes before A-frag reads

        // ---- x_spa = P @ v ; x1 = 0.1*x_spa + 0.95*v (packed bf16) ----
        f32x4 pa[4];
        #pragma unroll
        for (int nt = 0; nt < 4; ++nt) pa[nt] = (f32x4){0.f,0.f,0.f,0.f};
        #pragma unroll
        for (int kk = 0; kk < 2; ++kk) {
            bf16x8 a = *(const bf16x8*)&qP[arow][32 * kk + 8 * qd];
            #pragma unroll
            for (int nt = 0; nt < 4; ++nt) {
                bf16x8 bb = *(const bf16x8*)&vt[16 * nt + l15][32 * kk + 8 * qd];
                pa[nt] = MFMA(a, bb, pa[nt]);
            }
        }
        #pragma unroll
        for (int nt = 0; nt < 4; ++nt) {
            x1p[4 * h + nt][0] = pack2(0.1f * pa[nt][0] + 0.95f * vf[nt][0],
                                       0.1f * pa[nt][1] + 0.95f * vf[nt][1]);
            x1p[4 * h + nt][1] = pack2(0.1f * pa[nt][2] + 0.95f * vf[nt][2],
                                       0.1f * pa[nt][3] + 0.95f * vf[nt][3]);
        }
    }
    LGKM0(); BAR();   // attention fully done; xb may alias attn buffers now

    // ---- x1 -> xb (bf16, row-private), reload A-frags ----
    #pragma unroll
    for (int c = 0; c < 16; ++c)
        #pragma unroll
        for (int rp = 0; rp < 2; ++rp) {
            xb[16 * w + 4 * qd + 2 * rp    ][16 * c + l15] = (short)(x1p[c][rp] & 0xffff);
            xb[16 * w + 4 * qd + 2 * rp + 1][16 * c + l15] = (short)(x1p[c][rp] >> 16);
        }
    LGKM0();
    #pragma unroll
    for (int kk = 0; kk < 8; ++kk) ax[kk] = *(const bf16x8*)&xb[arow][32 * kk + 8 * qd];

    // ---- FFN-in + residual + sigmoid-residual ----
    #pragma unroll
    for (int half = 0; half < 2; ++half) {
        float bi[8];
        #pragma unroll
        for (int c = 0; c < 8; ++c) bi[c] = Bias[3 * DIM + 16 * (8 * half + c) + l15];
        f32x4 f[8];
        #pragma unroll
        for (int c = 0; c < 8; ++c) f[c] = (f32x4){0.f,0.f,0.f,0.f};
        #pragma unroll
        for (int kk = 0; kk < 8; ++kk) {
            const int fc = half * 8 + kk;
            vmwait<2>();
            BAR();
            const short* slot = (const short*)(fst + (fc & 1) * 8192);
            bf16x8 a = ax[kk];
            #pragma unroll
            for (int c = 0; c < 8; ++c)
                f[c] = MFMA(a, *(const bf16x8*)(slot + c * 512 + lane * 8), f[c]);
            LGKM0();
            BAR();
            issue_ffn(Wf, fst, fc + 2, w, lane);   // fc+2 <= 17, always valid here
        }
        #pragma unroll
        for (int c = 0; c < 8; ++c) {
            const int cg = 8 * half + c;
            #pragma unroll
            for (int rp = 0; rp < 2; ++rp) {
                float lo = bf2f(x1p[cg][rp] & 0xffff);
                float hi = bf2f(x1p[cg][rp] >> 16);
                float x2a = 0.1f * (f[c][2 * rp]     + bi[c]) + 0.95f * lo;
                float x2b = 0.1f * (f[c][2 * rp + 1] + bi[c]) + 0.95f * hi;
                float x3a = 0.95f * x2a + 0.1f * (1.0f / (1.0f + __expf(-x2a)) - 0.5f);
                float x3b = 0.95f * x2b + 0.1f * (1.0f / (1.0f + __expf(-x2b)) - 0.5f);
                x1p[cg][rp] = pack2(x3a, x3b);
            }
        }
    }

    // ---- x3 -> xb, reload A-frags ----
    #pragma unroll
    for (int c = 0; c < 16; ++c)
        #pragma unroll
        for (int rp = 0; rp < 2; ++rp) {
            xb[16 * w + 4 * qd + 2 * rp    ][16 * c + l15] = (short)(x1p[c][rp] & 0xffff);
            xb[16 * w + 4 * qd + 2 * rp + 1][16 * c + l15] = (short)(x1p[c][rp] >> 16);
        }
    LGKM0();
    #pragma unroll
    for (int kk = 0; kk < 8; ++kk) ax[kk] = *(const bf16x8*)&xb[arow][32 * kk + 8 * qd];
    LGKM0(); BAR();   // all waves hold x3 frags; stg may now clobber xb

    // ---- FFN-out + final residual, staged fp32 -> coalesced 512 B stores ----
    #pragma unroll
    for (int half = 0; half < 2; ++half) {
        float bo[8];
        #pragma unroll
        for (int c = 0; c < 8; ++c) bo[c] = Bias[4 * DIM + 16 * (8 * half + c) + l15];
        f32x4 f[8];
        #pragma unroll
        for (int c = 0; c < 8; ++c) f[c] = (f32x4){0.f,0.f,0.f,0.f};
        #pragma unroll
        for (int kk = 0; kk < 8; ++kk) {
            const int fc = 16 + half * 8 + kk;
            if (fc == 31) vmwait<0>(); else vmwait<2>();   // <2> over-waits safely
            BAR();                                          // past stores/bias ops
            const short* slot = (const short*)(fst + (fc & 1) * 8192);
            bf16x8 a = ax[kk];
            #pragma unroll
            for (int c = 0; c < 8; ++c)
                f[c] = MFMA(a, *(const bf16x8*)(slot + c * 512 + lane * 8), f[c]);
            LGKM0();
            BAR();
            if (fc + 2 < 32) issue_ffn(Wf, fst, fc + 2, w, lane);
        }
        #pragma unroll
        for (int c = 0; c < 8; ++c) {
            const int cg = 8 * half + c;
            #pragma unroll
            for (int rp = 0; rp < 2; ++rp) {
                float lo = bf2f(x1p[cg][rp] & 0xffff);
                float hi = bf2f(x1p[cg][rp] >> 16);
                stg[16 * w + 4 * qd + 2 * rp    ][16 * c + l15] = 0.1f * (f[c][2 * rp]     + bo[c]) + 0.95f * lo;
                stg[16 * w + 4 * qd + 2 * rp + 1][16 * c + l15] = 0.1f * (f[c][2 * rp + 1] + bo[c]) + 0.95f * hi;
            }
        }
        LGKM0();   // stg writes complete (same-wave cross-lane)
        #pragma unroll
        for (int it = 0; it < 8; ++it) {
            const int row = 16 * w + 2 * it + (lane >> 5);
            if (row < NTOK) {
                f32x4 vv = *(const f32x4*)&stg[row][4 * (lane & 31)];
                __builtin_nontemporal_store(vv,
                    (f32x4*)(oblk + row * DIM + 128 * half + 4 * (lane & 31)));
            }
        }
        LGKM0();   // stg reads complete before next half overwrites
    }
}

extern "C" void kernel_launch(void* const* d_in, const int* in_sizes, int n_in,
                              void* d_out, int out_size, void* d_ws, size_t ws_size,
                              hipStream_t stream) {
    const float* x = (const float*)d_in[0];
    short* Wf  = (short*)d_ws;                                        // 5*128 tiles * 1 KB
    float* Bias = (float*)((char*)d_ws + (size_t)5 * DIM * DIM * 2);  // 5*256 fp32
    prep_w<<<dim3(DIM, 5), 64, 0, stream>>>(
        (const float*)d_in[1], (const float*)d_in[3], (const float*)d_in[5],
        (const float*)d_in[7], (const float*)d_in[9], Wf);
    prep_b<<<dim3(NH, 5), 64, 0, stream>>>(
        (const float*)d_in[2], (const float*)d_in[4], (const float*)d_in[6],
        (const float*)d_in[8], (const float*)d_in[10], Bias);
    const int B = in_sizes[0] / (NTOK * DIM);
    irmb_main<<<B, 256, 0, stream>>>(x, Wf, Bias, (float*)d_out);
}

// Round 3
// 632.983 us; speedup vs baseline: 2.0413x; 1.3225x over previous
//
#include <hip/hip_runtime.h>

#define DIM  256
#define NH   4
#define HC   64
#define NTOK 49

typedef short bf16x8 __attribute__((ext_vector_type(8)));
typedef float f32x4  __attribute__((ext_vector_type(4)));

#define MFMA(a, b, c) __builtin_amdgcn_mfma_f32_16x16x32_bf16((a), (b), (c), 0, 0, 0)
#define LGKM0() asm volatile("s_waitcnt lgkmcnt(0)" ::: "memory")
#define BAR()   __builtin_amdgcn_s_barrier()
#define FENCE() asm volatile("" ::: "memory")

template<int N> __device__ __forceinline__ void vmwait() {
    asm volatile("s_waitcnt vmcnt(%0)" :: "n"(N) : "memory");
}

// async global->LDS, 16B per lane; LDS dest is wave-uniform base + lane*16
__device__ __forceinline__ void gload16(const void* g, void* l) {
    __builtin_amdgcn_global_load_lds(
        (const __attribute__((address_space(1))) unsigned int*)g,
        (__attribute__((address_space(3))) unsigned int*)l, 16, 0, 0);
}

// HW packed convert: lo16 = bf16(lo), hi16 = bf16(hi), RNE.
__device__ __forceinline__ unsigned pk2(float lo, float hi) {
    unsigned r;
    asm("v_cvt_pk_bf16_f32 %0, %1, %2" : "=v"(r) : "v"(lo), "v"(hi));
    return r;
}
__device__ __forceinline__ float bf2f(unsigned lo16) {
    union { unsigned u; float f; } v; v.u = lo16 << 16; return v.f;
}
__device__ __forceinline__ short f2bf(float f) {   // prep kernels only
    union { float f; unsigned u; } v; v.f = f;
    unsigned r = v.u + 0x7fffu + ((v.u >> 16) & 1u);   // RNE
    return (short)(r >> 16);
}
__device__ __forceinline__ float wred_sum16(float v) {
    v += __shfl_xor(v, 1); v += __shfl_xor(v, 2);
    v += __shfl_xor(v, 4); v += __shfl_xor(v, 8);
    return v;
}
__device__ __forceinline__ float wred_max16(float v) {
    v = fmaxf(v, __shfl_xor(v, 1)); v = fmaxf(v, __shfl_xor(v, 2));
    v = fmaxf(v, __shfl_xor(v, 4)); v = fmaxf(v, __shfl_xor(v, 8));
    return v;
}

// ---- chunk issue helpers -------------------------------------------------
// QKV chunk qc in [0,48): body b=qc/6 -> (h=b>>1, H=b&1); m=qc%6 -> (mat=m>>1,
// khalf=m&1). Chunk = 8 contiguous Wf tiles: (t in {0,1}) x (k4 in 0..3),
// tile = (mat*16 + h*4 + 2H + t)*8 + khalf*4 + k4. Wave w loads j = 2w, 2w+1
// where j = t*4+k4 (2 gloads -> vmcnt +=2 per wave). 3-slot ring, slot qc%3.
__device__ __forceinline__ void issue_qkv(const short* __restrict__ Wf, char* wst,
                                          int qc, int w, int lane) {
    const int b = qc / 6, m = qc % 6;
    const int h = b >> 1, H = b & 1, mat = m >> 1, kh = m & 1;
    char* slot = wst + (qc % 3) * 8192;
    const int tile0 = (mat * 16 + h * 4 + 2 * H) * 8 + kh * 4;
    #pragma unroll
    for (int i = 0; i < 2; ++i) {
        const int j = 2 * w + i, t = j >> 2, k4 = j & 3;
        gload16(Wf + (size_t)(tile0 + t * 8 + k4) * 512 + lane * 8, slot + j * 1024);
    }
}

// FFN chunk fc in [0,32): (g,hf,kk) = (fc>>4, (fc>>3)&1, fc&7). 8 tiles
// (c-groups 0..7), tile = (48 + g*16 + hf*8 + c)*8 + kk. Wave w loads c=2w,2w+1.
// Same 3-slot ring region as QKV (QKV stream is dead before first FFN issue).
__device__ __forceinline__ void issue_ffn(const short* __restrict__ Wf, char* wst,
                                          int fc, int w, int lane) {
    const int g = fc >> 4, hf = (fc >> 3) & 1, kk = fc & 7;
    char* slot = wst + (fc % 3) * 8192;
    #pragma unroll
    for (int i = 0; i < 2; ++i) {
        const int c = 2 * w + i;
        gload16(Wf + (size_t)((48 + g * 16 + hf * 8 + c) * 8 + kk) * 512 + lane * 8,
                slot + c * 1024);
    }
}

// Weight standardization + scatter into MFMA-fragment-major layout (unchanged).
__global__ void prep_w(const float* w0, const float* w1, const float* w2,
                       const float* w3, const float* w4, short* __restrict__ Wf) {
    const float* Ws[5] = {w0, w1, w2, w3, w4};
    const int mat  = blockIdx.y;
    const int k    = blockIdx.x;
    const int lane = threadIdx.x;
    const float* W = Ws[mat];
    #pragma unroll
    for (int h = 0; h < NH; ++h) {
        float w = W[k * DIM + h * HC + lane];
        float s1 = w, s2 = w * w;
        #pragma unroll
        for (int off = 1; off < 64; off <<= 1) {
            s1 += __shfl_xor(s1, off);
            s2 += __shfl_xor(s2, off);
        }
        float m   = s1 * 0.015625f;
        float var = s2 * 0.015625f - m * m;
        float inv = rsqrtf(fmaxf(var, 1e-30f)) * 0.0625f;
        float val = (w - m) * inv;
        int n  = h * HC + lane;
        int nt = n >> 4, nl = n & 15;
        int kk = k >> 5, kl = k & 31;
        Wf[((mat * 16 + nt) * 8 + kk) * 512 + (nl + 16 * (kl >> 3)) * 8 + (kl & 7)] = f2bf(val);
    }
}

__global__ void prep_b(const float* b0, const float* b1, const float* b2,
                       const float* b3, const float* b4, float* __restrict__ Bias) {
    const float* Bs[5] = {b0, b1, b2, b3, b4};
    const int mat = blockIdx.y, h = blockIdx.x, lane = threadIdx.x;
    float w = Bs[mat][h * HC + lane];
    float s1 = w, s2 = w * w;
    #pragma unroll
    for (int off = 1; off < 64; off <<= 1) {
        s1 += __shfl_xor(s1, off);
        s2 += __shfl_xor(s2, off);
    }
    float m   = s1 * 0.015625f;
    float var = s2 * 0.015625f - m * m;
    float inv = rsqrtf(fmaxf(var, 1e-30f)) * 0.0625f;
    Bias[mat * DIM + h * HC + lane] = (w - m) * inv;
}

// ---- phase macros: 3-deep ring, ONE barrier per phase, counted vmcnt ----
// Safety: a wave's ds_reads of chunk p complete before its MFMAs (compiler
// lgkm waits), which precede its next-phase BAR; issue into slot (p-1)%3
// happens after that BAR -> no overwrite race. vmcnt counts are exact per
// wave: every counted load is unconditional and pinned by FENCE regions.

#define QPHASE16(QCV, AXH, A0, A1)                                        \
  { const int qc_ = (QCV);                                                \
    LGKM0(); vmwait<16>(); BAR();                                         \
    issue_qkv(Wf, wst, qc_ + 2, w, lane);                                 \
    const short* sl_ = (const short*)(wst + (qc_ % 3) * 8192);            \
    _Pragma("unroll")                                                     \
    for (int k4_ = 0; k4_ < 4; ++k4_) {                                   \
        bf16x8 a_  = ax[(AXH) * 4 + k4_];                                 \
        bf16x8 b0_ = *(const bf16x8*)(sl_ + k4_ * 512 + lane * 8);        \
        bf16x8 b1_ = *(const bf16x8*)(sl_ + (4 + k4_) * 512 + lane * 8);  \
        A0 = MFMA(a_, b0_, A0); A1 = MFMA(a_, b1_, A1);                   \
    } FENCE(); }

#define QPHASE2(QCV, AXH, A0, A1)                                         \
  { const int qc_ = (QCV);                                                \
    LGKM0();                                                              \
    if (qc_ == 47) vmwait<0>(); else vmwait<2>();                         \
    BAR();                                                                \
    if (qc_ < 46) issue_qkv(Wf, wst, qc_ + 2, w, lane);                   \
    else if (qc_ == 47) { issue_ffn(Wf, wst, 0, w, lane);                 \
                          issue_ffn(Wf, wst, 1, w, lane); }               \
    const short* sl_ = (const short*)(wst + (qc_ % 3) * 8192);            \
    _Pragma("unroll")                                                     \
    for (int k4_ = 0; k4_ < 4; ++k4_) {                                   \
        bf16x8 a_  = ax[(AXH) * 4 + k4_];                                 \
        bf16x8 b0_ = *(const bf16x8*)(sl_ + k4_ * 512 + lane * 8);        \
        bf16x8 b1_ = *(const bf16x8*)(sl_ + (4 + k4_) * 512 + lane * 8);  \
        A0 = MFMA(a_, b0_, A0); A1 = MFMA(a_, b1_, A1);                   \
    } FENCE(); }

#define FPHASE(FCV, KKI)                                                  \
  { const int fc_ = (FCV), kkl_ = (KKI);                                  \
    LGKM0();                                                              \
    if (kkl_ < 2)       vmwait<10>();                                     \
    else if (fc_ == 31) vmwait<0>();                                      \
    else                vmwait<2>();                                      \
    BAR();                                                                \
    if (fc_ < 30) issue_ffn(Wf, wst, fc_ + 2, w, lane);                   \
    const short* sl_ = (const short*)(wst + (fc_ % 3) * 8192);            \
    bf16x8 a_ = ax[kkl_];                                                 \
    _Pragma("unroll")                                                     \
    for (int c_ = 0; c_ < 8; ++c_)                                        \
        f[c_] = MFMA(a_, *(const bf16x8*)(sl_ + c_ * 512 + lane * 8), f[c_]); \
    FENCE(); }

// One block = one batch item; 4 waves, wave w owns token rows [16w,16w+16).
// LDS map: [0,26400) xb/stg (FFN phases) inside [0,27648) qP/kb/vt (attn);
//          [27648,52224) = 3 x 8 KB weight-chunk ring (QKV then FFN stream).
__global__ __launch_bounds__(256, 3) void irmb_main(
    const float* __restrict__ x, const short* __restrict__ Wf,
    const float* __restrict__ Bias, float* __restrict__ out)
{
    __shared__ __align__(16) char smem[52224];
    short (*qP)[72]  = (short (*)[72])smem;            //  9216 B
    short (*kb)[72]  = (short (*)[72])(smem +  9216);  //  9216 B
    short (*vt)[72]  = (short (*)[72])(smem + 18432);  //  9216 B
    short (*xb)[264] = (short (*)[264])smem;           // 50 rows x 528 B
    float (*stg)[132] = (float (*)[132])smem;          // 50 rows x 528 B
    char* wst = smem + 27648;                          // 3 x 8192 ring

    const int tid = threadIdx.x;
    const int w = tid >> 6, lane = tid & 63;
    const int l15 = lane & 15, qd = lane >> 4;
    const int arow = 16 * w + l15;

    const float* xblk = x + (size_t)blockIdx.x * (NTOK * DIM);
    float* oblk = out + (size_t)blockIdx.x * (NTOK * DIM);

    // ---- x A-fragments, nontemporal (keep x out of L2 so Wf stays hot) ----
    bf16x8 ax[8];
    {
        const float* xr = xblk + arow * DIM;
        #pragma unroll
        for (int kk = 0; kk < 8; ++kk) {
            f32x4 u = {0.f,0.f,0.f,0.f}, v2 = {0.f,0.f,0.f,0.f};
            if (arow < NTOK) {
                u  = __builtin_nontemporal_load((const f32x4*)(xr + 32 * kk + 8 * qd));
                v2 = __builtin_nontemporal_load((const f32x4*)(xr + 32 * kk + 8 * qd + 4));
            }
            union { bf16x8 v; unsigned u4[4]; } t;
            t.u4[0] = pk2(u[0],  u[1]);  t.u4[1] = pk2(u[2],  u[3]);
            t.u4[2] = pk2(v2[0], v2[1]); t.u4[3] = pk2(v2[2], v2[3]);
            ax[kk] = t.v;
        }
    }

    // prologue: chunks 0,1 in flight
    issue_qkv(Wf, wst, 0, w, lane);
    issue_qkv(Wf, wst, 1, w, lane);
    FENCE();

    unsigned x1p[16][2];   // packed bf16 x1 (later x3), C-layout row pairs

    #pragma unroll
    for (int h = 0; h < NH; ++h) {
        float vf[4][4];
        unsigned kp[4][2];

        #pragma unroll
        for (int H = 0; H < 2; ++H) {
            const int C = (h * 2 + H) * 6;

            // body-top loads (exactly 14 vm ops per wave, unconditional)
            float xh[2][4], bq_[2], bk_[2], bv_[2];
            #pragma unroll
            for (int t = 0; t < 2; ++t) {
                const int col = h * HC + 16 * (2 * H + t) + l15;
                bq_[t] = Bias[col]; bk_[t] = Bias[DIM + col]; bv_[t] = Bias[2 * DIM + col];
                #pragma unroll
                for (int r = 0; r < 4; ++r) {
                    const int row = 16 * w + 4 * qd + r;
                    const int rr  = row < NTOK ? row : 0;
                    float xv = __builtin_nontemporal_load(xblk + rr * DIM + col);
                    xh[t][r] = row < NTOK ? xv : 0.f;
                }
            }
            FENCE();

            f32x4 qa[2], ka[2], va[2];
            #pragma unroll
            for (int t = 0; t < 2; ++t) {
                qa[t] = (f32x4){0.f,0.f,0.f,0.f};
                ka[t] = (f32x4){0.f,0.f,0.f,0.f};
                va[t] = (f32x4){0.f,0.f,0.f,0.f};
            }

            QPHASE16(C + 0, 0, qa[0], qa[1])
            QPHASE16(C + 1, 1, qa[0], qa[1])
            QPHASE2 (C + 2, 0, ka[0], ka[1])
            QPHASE2 (C + 3, 1, ka[0], ka[1])
            QPHASE2 (C + 4, 0, va[0], va[1])
            QPHASE2 (C + 5, 1, va[0], va[1])

            #pragma unroll
            for (int t = 0; t < 2; ++t) {
                const int nt = 2 * H + t;
                const int rw = 16 * w + 4 * qd;
                unsigned q01 = pk2(qa[t][0] + bq_[t], qa[t][1] + bq_[t]);
                unsigned q23 = pk2(qa[t][2] + bq_[t], qa[t][3] + bq_[t]);
                qP[rw    ][16 * nt + l15] = (short)q01;
                qP[rw + 1][16 * nt + l15] = (short)(q01 >> 16);
                qP[rw + 2][16 * nt + l15] = (short)q23;
                qP[rw + 3][16 * nt + l15] = (short)(q23 >> 16);
                #pragma unroll
                for (int r = 0; r < 4; ++r)
                    vf[nt][r] = 0.1f * (va[t][r] + bv_[t]) + 0.95f * xh[t][r];
                kp[nt][0] = pk2(ka[t][0] + bk_[t], ka[t][1] + bk_[t]);
                kp[nt][1] = pk2(ka[t][2] + bk_[t], ka[t][3] + bk_[t]);
            }
        }

        if (h) { LGKM0(); BAR(); }       // prior head's kb/vt reads complete
        #pragma unroll
        for (int nt = 0; nt < 4; ++nt) {
            const int rw = 16 * w + 4 * qd;
            kb[rw    ][16 * nt + l15] = (short)kp[nt][0];
            kb[rw + 1][16 * nt + l15] = (short)(kp[nt][0] >> 16);
            kb[rw + 2][16 * nt + l15] = (short)kp[nt][1];
            kb[rw + 3][16 * nt + l15] = (short)(kp[nt][1] >> 16);
            uint2 vv;
            vv.x = pk2(vf[nt][0], vf[nt][1]);
            vv.y = pk2(vf[nt][2], vf[nt][3]);
            *(uint2*)&vt[16 * nt + l15][rw] = vv;   // [channel][token]
        }
        LGKM0(); BAR();                  // kb/vt ready (lgkm only)

        // ---- S = 0.125 * q @ k^T ----
        f32x4 sa[4];
        #pragma unroll
        for (int nt = 0; nt < 4; ++nt) sa[nt] = (f32x4){0.f,0.f,0.f,0.f};
        #pragma unroll
        for (int kk = 0; kk < 2; ++kk) {
            bf16x8 a = *(const bf16x8*)&qP[arow][32 * kk + 8 * qd];
            #pragma unroll
            for (int nt = 0; nt < 4; ++nt) {
                bf16x8 bb = *(const bf16x8*)&kb[16 * nt + l15][32 * kk + 8 * qd];
                sa[nt] = MFMA(a, bb, sa[nt]);
            }
        }

        // ---- softmax over keys (mask cols >= 49) ----
        float pmat[4][4];
        #pragma unroll
        for (int r = 0; r < 4; ++r) {
            float vals[4];
            #pragma unroll
            for (int nt = 0; nt < 4; ++nt) {
                const int ck = 16 * nt + l15;
                vals[nt] = (ck < NTOK) ? sa[nt][r] * 0.125f : -3.0e38f;
            }
            float mx = fmaxf(fmaxf(vals[0], vals[1]), fmaxf(vals[2], vals[3]));
            mx = wred_max16(mx);
            float sum = 0.f;
            #pragma unroll
            for (int nt = 0; nt < 4; ++nt) {
                const int ck = 16 * nt + l15;
                const float p = (ck < NTOK) ? __expf(vals[nt] - mx) : 0.f;
                pmat[nt][r] = p;
                sum += p;
            }
            sum = wred_sum16(sum);
            const float rs = 1.0f / sum;
            #pragma unroll
            for (int nt = 0; nt < 4; ++nt) pmat[nt][r] *= rs;
        }
        #pragma unroll
        for (int nt = 0; nt < 4; ++nt) {
            const int rw = 16 * w + 4 * qd;
            unsigned p01 = pk2(pmat[nt][0], pmat[nt][1]);
            unsigned p23 = pk2(pmat[nt][2], pmat[nt][3]);
            qP[rw    ][16 * nt + l15] = (short)p01;
            qP[rw + 1][16 * nt + l15] = (short)(p01 >> 16);
            qP[rw + 2][16 * nt + l15] = (short)p23;
            qP[rw + 3][16 * nt + l15] = (short)(p23 >> 16);
        }
        LGKM0();   // same-wave cross-lane: P writes before A-frag reads

        // ---- x_spa = P @ v ; x1 = 0.1*x_spa + 0.95*v (packed bf16) ----
        f32x4 pa[4];
        #pragma unroll
        for (int nt = 0; nt < 4; ++nt) pa[nt] = (f32x4){0.f,0.f,0.f,0.f};
        #pragma unroll
        for (int kk = 0; kk < 2; ++kk) {
            bf16x8 a = *(const bf16x8*)&qP[arow][32 * kk + 8 * qd];
            #pragma unroll
            for (int nt = 0; nt < 4; ++nt) {
                bf16x8 bb = *(const bf16x8*)&vt[16 * nt + l15][32 * kk + 8 * qd];
                pa[nt] = MFMA(a, bb, pa[nt]);
            }
        }
        #pragma unroll
        for (int nt = 0; nt < 4; ++nt) {
            x1p[4 * h + nt][0] = pk2(0.1f * pa[nt][0] + 0.95f * vf[nt][0],
                                     0.1f * pa[nt][1] + 0.95f * vf[nt][1]);
            x1p[4 * h + nt][1] = pk2(0.1f * pa[nt][2] + 0.95f * vf[nt][2],
                                     0.1f * pa[nt][3] + 0.95f * vf[nt][3]);
        }
    }
    LGKM0(); BAR();   // attention fully done; xb may alias attn buffers now

    // ---- x1 -> xb (bf16, row-private, 50 rows), reload A-frags ----
    #pragma unroll
    for (int c = 0; c < 16; ++c)
        #pragma unroll
        for (int rp = 0; rp < 2; ++rp) {
            const int r0 = 16 * w + 4 * qd + 2 * rp;
            if (r0 < 50)     xb[r0    ][16 * c + l15] = (short)(x1p[c][rp] & 0xffff);
            if (r0 + 1 < 50) xb[r0 + 1][16 * c + l15] = (short)(x1p[c][rp] >> 16);
        }
    LGKM0();
    const int xrow = arow < 50 ? arow : 49;
    #pragma unroll
    for (int kk = 0; kk < 8; ++kk) ax[kk] = *(const bf16x8*)&xb[xrow][32 * kk + 8 * qd];

    // ---- FFN-in + residual + sigmoid-residual ----
    #pragma unroll
    for (int hf = 0; hf < 2; ++hf) {
        float bi[8];
        #pragma unroll
        for (int c = 0; c < 8; ++c) bi[c] = Bias[3 * DIM + 16 * (8 * hf + c) + l15];
        FENCE();
        f32x4 f[8];
        #pragma unroll
        for (int c = 0; c < 8; ++c) f[c] = (f32x4){0.f,0.f,0.f,0.f};
        #pragma unroll
        for (int kk = 0; kk < 8; ++kk) FPHASE(hf * 8 + kk, kk)
        #pragma unroll
        for (int c = 0; c < 8; ++c) {
            const int cg = 8 * hf + c;
            #pragma unroll
            for (int rp = 0; rp < 2; ++rp) {
                float lo = bf2f(x1p[cg][rp] & 0xffff);
                float hi = bf2f(x1p[cg][rp] >> 16);
                float x2a = 0.1f * (f[c][2 * rp]     + bi[c]) + 0.95f * lo;
                float x2b = 0.1f * (f[c][2 * rp + 1] + bi[c]) + 0.95f * hi;
                float x3a = 0.95f * x2a + 0.1f * (1.0f / (1.0f + __expf(-x2a)) - 0.5f);
                float x3b = 0.95f * x2b + 0.1f * (1.0f / (1.0f + __expf(-x2b)) - 0.5f);
                x1p[cg][rp] = pk2(x3a, x3b);
            }
        }
    }

    // ---- x3 -> xb, reload A-frags ----
    #pragma unroll
    for (int c = 0; c < 16; ++c)
        #pragma unroll
        for (int rp = 0; rp < 2; ++rp) {
            const int r0 = 16 * w + 4 * qd + 2 * rp;
            if (r0 < 50)     xb[r0    ][16 * c + l15] = (short)(x1p[c][rp] & 0xffff);
            if (r0 + 1 < 50) xb[r0 + 1][16 * c + l15] = (short)(x1p[c][rp] >> 16);
        }
    LGKM0();
    #pragma unroll
    for (int kk = 0; kk < 8; ++kk) ax[kk] = *(const bf16x8*)&xb[xrow][32 * kk + 8 * qd];
    LGKM0(); BAR();   // all waves hold x3 frags; stg may now clobber xb

    // ---- FFN-out + final residual, staged fp32 -> coalesced 512 B stores ----
    #pragma unroll
    for (int hf = 0; hf < 2; ++hf) {
        float bo[8];
        #pragma unroll
        for (int c = 0; c < 8; ++c) bo[c] = Bias[4 * DIM + 16 * (8 * hf + c) + l15];
        FENCE();
        f32x4 f[8];
        #pragma unroll
        for (int c = 0; c < 8; ++c) f[c] = (f32x4){0.f,0.f,0.f,0.f};
        #pragma unroll
        for (int kk = 0; kk < 8; ++kk) FPHASE(16 + hf * 8 + kk, kk)
        #pragma unroll
        for (int c = 0; c < 8; ++c) {
            const int cg = 8 * hf + c;
            #pragma unroll
            for (int rp = 0; rp < 2; ++rp) {
                float lo = bf2f(x1p[cg][rp] & 0xffff);
                float hi = bf2f(x1p[cg][rp] >> 16);
                const int r0 = 16 * w + 4 * qd + 2 * rp;
                float s0 = 0.1f * (f[c][2 * rp]     + bo[c]) + 0.95f * lo;
                float s1 = 0.1f * (f[c][2 * rp + 1] + bo[c]) + 0.95f * hi;
                if (r0 < 50)     stg[r0    ][16 * c + l15] = s0;
                if (r0 + 1 < 50) stg[r0 + 1][16 * c + l15] = s1;
            }
        }
        LGKM0();   // stg writes complete (same-wave, row-private)
        #pragma unroll
        for (int it = 0; it < 8; ++it) {
            const int row = 16 * w + 2 * it + (lane >> 5);
            if (row < NTOK) {
                f32x4 vv = *(const f32x4*)&stg[row][4 * (lane & 31)];
                __builtin_nontemporal_store(vv,
                    (f32x4*)(oblk + row * DIM + 128 * hf + 4 * (lane & 31)));
            }
        }
        LGKM0();            // stg reads complete before next half overwrites
        if (hf == 0) vmwait<0>();   // drain divergent store counts before bo1
        FENCE();
    }
}

extern "C" void kernel_launch(void* const* d_in, const int* in_sizes, int n_in,
                              void* d_out, int out_size, void* d_ws, size_t ws_size,
                              hipStream_t stream) {
    const float* x = (const float*)d_in[0];
    short* Wf  = (short*)d_ws;                                        // 5*128 tiles * 1 KB
    float* Bias = (float*)((char*)d_ws + (size_t)5 * DIM * DIM * 2);  // 5*256 fp32
    prep_w<<<dim3(DIM, 5), 64, 0, stream>>>(
        (const float*)d_in[1], (const float*)d_in[3], (const float*)d_in[5],
        (const float*)d_in[7], (const float*)d_in[9], Wf);
    prep_b<<<dim3(NH, 5), 64, 0, stream>>>(
        (const float*)d_in[2], (const float*)d_in[4], (const float*)d_in[6],
        (const float*)d_in[8], (const float*)d_in[10], Bias);
    const int B = in_sizes[0] / (NTOK * DIM);
    irmb_main<<<B, 256, 0, stream>>>(x, Wf, Bias, (float*)d_out);
}